// Round 5
// baseline (349.843 us; speedup 1.0000x reference)
//
#include <hip/hip_runtime.h>
#include <stdint.h>
#include <stddef.h>

#define DIMC 1024
#define LSEQ 2048
#define BSZ  4
#define DFFC 4096
#define NTOK (BSZ*LSEQ)   // 8192 tokens
#define NCHUNK 32
#define CHUNK 64          // NCHUNK*CHUNK == LSEQ

typedef __bf16 bf16x8 __attribute__((ext_vector_type(8)));
typedef float  f32x4  __attribute__((ext_vector_type(4)));

__device__ __forceinline__ unsigned short f2bf(float f) {
  unsigned int u = __float_as_uint(f);
  u += 0x7fffu + ((u >> 16) & 1u);      // RNE
  return (unsigned short)(u >> 16);
}

__device__ __forceinline__ void async16(const void* g, void* l) {
  __builtin_amdgcn_global_load_lds(
      (const __attribute__((address_space(1))) unsigned int*)(uintptr_t)g,
      (__attribute__((address_space(3))) unsigned int*)(uintptr_t)l,
      16, 0, 0);
}

__device__ __forceinline__ void bar() {
  asm volatile("" ::: "memory");
  __builtin_amdgcn_s_barrier();
  asm volatile("" ::: "memory");
}
#define LGKM0 do { asm volatile("s_waitcnt lgkmcnt(0)" ::: "memory"); \
                   __builtin_amdgcn_sched_barrier(0); } while (0)
#define VMCNT(n) asm volatile("s_waitcnt vmcnt(" #n ")" ::: "memory")
template <int N> __device__ __forceinline__ void vmwait() {
  if constexpr (N == 0) VMCNT(0);
  else if constexpr (N == 3) VMCNT(3);
  else if constexpr (N == 4) VMCNT(4);
  else if constexpr (N == 6) VMCNT(6);
  else if constexpr (N == 8) VMCNT(8);
}
#define MFMA_BF16 __builtin_amdgcn_mfma_f32_16x16x32_bf16

// ---------------- prep: transposes + LN1 stats + tokstat zero, one launch ----
// blocks [0,4096): transpose w1 [DIMC][DFFC] -> w1t [DFFC][DIMC] bf16
// blocks [4096,8192): transpose w2 [DFFC][DIMC] -> w2t [DIMC][DFFC] bf16
// blocks [8192,16384): LN stats of x token (blk-8192); also zero tokstat
__global__ __launch_bounds__(256) void prep(const float* __restrict__ w1,
                                            const float* __restrict__ w2,
                                            unsigned short* __restrict__ w1t,
                                            unsigned short* __restrict__ w2t,
                                            const float* __restrict__ x,
                                            float* __restrict__ mu,
                                            float* __restrict__ rstd,
                                            float* __restrict__ tokstat) {
  __shared__ float tile[32][33];
  __shared__ float sh[8];
  const int blk = blockIdx.x;
  if (blk < 8192) {
    const float* w; unsigned short* wt; int K, N, bi;
    if (blk < 4096) { w = w1; wt = w1t; K = DIMC; N = DFFC; bi = blk; }
    else            { w = w2; wt = w2t; K = DFFC; N = DIMC; bi = blk - 4096; }
    const int nbx = N / 32;
    const int n0 = (bi % nbx) * 32, k0 = (bi / nbx) * 32;
    const int tx = threadIdx.x & 31, ty = threadIdx.x >> 5;  // 32 x 8
    #pragma unroll
    for (int i = 0; i < 32; i += 8)
      tile[ty + i][tx] = w[(size_t)(k0 + ty + i) * N + n0 + tx];
    __syncthreads();
    #pragma unroll
    for (int i = 0; i < 32; i += 8)
      wt[(size_t)(n0 + ty + i) * K + k0 + tx] = f2bf(tile[tx][ty + i]);
  } else {
    const int token = blk - 8192;
    const float4* xp = (const float4*)(x + (size_t)token * DIMC);
    float4 v = xp[threadIdx.x];
    float s  = v.x + v.y + v.z + v.w;
    float s2 = v.x*v.x + v.y*v.y + v.z*v.z + v.w*v.w;
    #pragma unroll
    for (int o = 32; o; o >>= 1) { s += __shfl_down(s, o); s2 += __shfl_down(s2, o); }
    const int lane = threadIdx.x & 63, w = threadIdx.x >> 6;
    if (lane == 0) { sh[w] = s; sh[4 + w] = s2; }
    __syncthreads();
    if (threadIdx.x == 0) {
      float ts  = sh[0] + sh[1] + sh[2] + sh[3];
      float ts2 = sh[4] + sh[5] + sh[6] + sh[7];
      float m = ts * (1.f / DIMC);
      float var = ts2 * (1.f / DIMC) - m * m;
      mu[token] = m;
      rstd[token] = rsqrtf(var + 1e-5f);
      tokstat[2 * token] = 0.f;          // zero for scan_phase3 atomics
      tokstat[2 * token + 1] = 0.f;
    }
  }
}

// ---------------- spiral scan ----------------
__device__ __forceinline__ void get_p(const float* __restrict__ phazor, int d,
                                      float& p_re, float& p_im) {
  float pre = phazor[2 * d], pim = phazor[2 * d + 1];
  float a = sqrtf(pre * pre + pim * pim);
  float sc = expf(-a) / a;
  p_re = pre * sc;
  p_im = pim * sc;
}

__global__ __launch_bounds__(256) void scan_phase1(const float* __restrict__ x,
                                                   const float* __restrict__ mu,
                                                   const float* __restrict__ rstd,
                                                   const float* __restrict__ g,
                                                   const float* __restrict__ bb,
                                                   const float* __restrict__ phazor,
                                                   float* __restrict__ Sre,
                                                   float* __restrict__ Sim) {
  const int d = blockIdx.x * 256 + threadIdx.x;
  const int c = blockIdx.y;
  const int b = blockIdx.z;
  float p_re, p_im; get_p(phazor, d, p_re, p_im);
  const float gd = g[d], bd = bb[d];
  const int t0 = c * CHUNK;
  const float* xp  = x + ((size_t)(b * LSEQ + t0)) * DIMC + d;
  const float* mup = mu + b * LSEQ + t0;
  const float* rp  = rstd + b * LSEQ + t0;
  float r_re = 0.f, r_im = 0.f;
  #pragma unroll
  for (int s8 = 0; s8 < CHUNK; s8 += 8) {
    float xv[8];
    #pragma unroll
    for (int k = 0; k < 8; ++k) xv[k] = xp[(size_t)(s8 + k) * DIMC];
    #pragma unroll
    for (int k = 0; k < 8; ++k) {
      float hv = (xv[k] - mup[s8 + k]) * rp[s8 + k] * gd + bd;
      float nr = p_re * r_re - p_im * r_im + hv;
      float ni = p_re * r_im + p_im * r_re;
      r_re = nr; r_im = ni;
    }
  }
  const int bd_i = b * DIMC + d;
  Sre[c * (BSZ * DIMC) + bd_i] = r_re;
  Sim[c * (BSZ * DIMC) + bd_i] = r_im;
}

// phase3: per-chunk replay. Computes its own chunk-prefix from S (no phase2),
// writes x2 = conv+resid, and accumulates per-token (sum,sum^2) of x2 via
// wave reduce + LDS + 2 atomicAdds per token (for LN2).
__global__ __launch_bounds__(256) void scan_phase3(const float* __restrict__ x,
                                                   const float* __restrict__ mu,
                                                   const float* __restrict__ rstd,
                                                   const float* __restrict__ g,
                                                   const float* __restrict__ bb,
                                                   const float* __restrict__ phazor,
                                                   const float* __restrict__ phazor_init,
                                                   const float* __restrict__ last_re,
                                                   const float* __restrict__ last_im,
                                                   const float* __restrict__ Sre,
                                                   const float* __restrict__ Sim,
                                                   float* __restrict__ x2,
                                                   float* __restrict__ tokstat) {
  __shared__ float shs[CHUNK][4], shs2[CHUNK][4];
  const int d = blockIdx.x * 256 + threadIdx.x;
  const int c = blockIdx.y;
  const int b = blockIdx.z;
  const int lane = threadIdx.x & 63, wv = threadIdx.x >> 6;
  float p_re, p_im; get_p(phazor, d, p_re, p_im);
  const float pi_re = phazor_init[2 * d], pi_im = phazor_init[2 * d + 1];
  const float gd = g[d], bd_ = bb[d];
  const int bd_i = b * DIMC + d;
  // p^64
  float br = p_re, bi = p_im;
  #pragma unroll
  for (int i = 0; i < 6; ++i) { float t = br * br - bi * bi; bi = 2.f * br * bi; br = t; }
  // chunk prefix: R = 0; for j<c: R = p64*R + S[j]   (batched loads, 8 deep)
  float r_re = 0.f, r_im = 0.f;
  for (int j0 = 0; j0 < c; j0 += 8) {
    float sr[8], si[8];
    const int jn = (c - j0 < 8) ? (c - j0) : 8;
    for (int k = 0; k < jn; ++k) {
      sr[k] = Sre[(j0 + k) * (BSZ * DIMC) + bd_i];
      si[k] = Sim[(j0 + k) * (BSZ * DIMC) + bd_i];
    }
    for (int k = 0; k < jn; ++k) {
      float nr = br * r_re - bi * r_im + sr[k];
      float ni = br * r_im + bi * r_re + si[k];
      r_re = nr; r_im = ni;
    }
  }
  // q = last * p^(64c): binary exponentiation of p^64 by c
  float er = 1.f, ei = 0.f;
  {
    float qr = br, qi = bi;
    int e = c;
    while (e) {
      if (e & 1) { float t = er * qr - ei * qi; ei = er * qi + ei * qr; er = t; }
      float t2 = qr * qr - qi * qi; qi = 2.f * qr * qi; qr = t2;
      e >>= 1;
    }
  }
  const float lre = last_re[bd_i], lim = last_im[bd_i];
  float q_re = lre * er - lim * ei;
  float q_im = lre * ei + lim * er;
  const int t0 = c * CHUNK;
  const float* xp  = x + ((size_t)(b * LSEQ + t0)) * DIMC + d;
  const float* mup = mu + b * LSEQ + t0;
  const float* rp  = rstd + b * LSEQ + t0;
  float* op = x2 + ((size_t)(b * LSEQ + t0)) * DIMC + d;
  #pragma unroll
  for (int s8 = 0; s8 < CHUNK; s8 += 8) {
    float xv[8];
    #pragma unroll
    for (int k = 0; k < 8; ++k) xv[k] = xp[(size_t)(s8 + k) * DIMC];
    #pragma unroll
    for (int k = 0; k < 8; ++k) {
      float hv = (xv[k] - mup[s8 + k]) * rp[s8 + k] * gd + bd_;
      float nr = p_re * r_re - p_im * r_im + hv;
      float ni = p_re * r_im + p_im * r_re;
      r_re = nr; r_im = ni;
      float nq = p_re * q_re - p_im * q_im;
      q_im = p_re * q_im + p_im * q_re;
      q_re = nq;
      float opv = pi_re * r_re - pi_im * r_im + q_re + xv[k];
      op[(size_t)(s8 + k) * DIMC] = opv;
      // per-token stats (64 lanes = 64 consecutive d of the same token)
      float a1 = opv, a2 = opv * opv;
      #pragma unroll
      for (int o = 32; o; o >>= 1) { a1 += __shfl_xor(a1, o); a2 += __shfl_xor(a2, o); }
      if (lane == 0) { shs[s8 + k][wv] = a1; shs2[s8 + k][wv] = a2; }
    }
  }
  __syncthreads();
  if (threadIdx.x < CHUNK) {
    const int s = threadIdx.x;
    float s1 = shs[s][0] + shs[s][1] + shs[s][2] + shs[s][3];
    float s2 = shs2[s][0] + shs2[s][1] + shs2[s][2] + shs2[s][3];
    const int tok = b * LSEQ + t0 + s;
    atomicAdd(&tokstat[2 * tok], s1);
    atomicAdd(&tokstat[2 * tok + 1], s2);
  }
}

// ---------------- LN2 apply (stats precomputed by phase3) -> bf16 ----------------
__global__ __launch_bounds__(256) void ln_apply(const float* __restrict__ x2,
                                                const float* __restrict__ tokstat,
                                                const float* __restrict__ g,
                                                const float* __restrict__ bb,
                                                unsigned short* __restrict__ out) {
  const int token = blockIdx.x;
  const float s1 = tokstat[2 * token], s2 = tokstat[2 * token + 1];
  const float m = s1 * (1.f / DIMC);
  const float var = s2 * (1.f / DIMC) - m * m;
  const float r = rsqrtf(var + 1e-5f);
  float4 v = ((const float4*)(x2 + (size_t)token * DIMC))[threadIdx.x];
  float4 gv = ((const float4*)g)[threadIdx.x];
  float4 bv = ((const float4*)bb)[threadIdx.x];
  ushort4 o;
  o.x = f2bf((v.x - m) * r * gv.x + bv.x);
  o.y = f2bf((v.y - m) * r * gv.y + bv.y);
  o.z = f2bf((v.z - m) * r * gv.z + bv.z);
  o.w = f2bf((v.w - m) * r * gv.w + bv.w);
  ((ushort4*)(out + (size_t)token * DIMC))[threadIdx.x] = o;
}

// ---------------- m201-style 8-phase MFMA GEMM (unchanged from round 4) ----------
template<int BN, int EPI>
__global__ __launch_bounds__(512, 2) void gemm8(const unsigned short* __restrict__ A,
                                                const unsigned short* __restrict__ Bt,
                                                const float* __restrict__ bias,
                                                const float* __restrict__ resid,
                                                void* __restrict__ outp,
                                                int M, int N, int K) {
  constexpr int AUS = 256 * 32;          // ushorts per A kk-block (16 KB)
  constexpr int BUS = BN * 32;           // ushorts per B kk-block
  constexpr int BUFUS = 2 * AUS + 2 * BUS;
  constexpr int NI = (BN == 256) ? 4 : 2;
  constexpr int LDSUS = (2 * BUFUS > 65536) ? 2 * BUFUS : 65536;
  __shared__ __align__(16) unsigned short lds[LDSUS];

  const int tid  = threadIdx.x;
  const int lane = tid & 63;
  const int wave = tid >> 6;
  const int wm = (wave & 1) * 128;
  const int wn = (wave >> 1) * (BN / 4);
  const int r15 = lane & 15;
  const int cus = ((lane >> 4) ^ ((r15 >> 1) & 3)) * 8;  // swizzled col (ushorts)

  int bid = blockIdx.x;                   // XCD-aware swizzle (grid % 8 == 0)
  const int cpx = gridDim.x >> 3;
  bid = (bid & 7) * cpx + (bid >> 3);
  const int ntn = N / BN;
  const int tm = (bid / ntn) * 256;
  const int tn = (bid % ntn) * BN;
  const int NT = K >> 6;                  // even (16 or 64)

  f32x4 acc[8][NI];
  #pragma unroll
  for (int i = 0; i < 8; ++i)
    #pragma unroll
    for (int j = 0; j < NI; ++j) acc[i][j] = (f32x4){0.f, 0.f, 0.f, 0.f};

  auto stageA1 = [&](int buf, int kk, int k0, int half) {   // one gload_lds
    unsigned short* blk = lds + buf * BUFUS + kk * AUS;
    const unsigned short* g = A + (size_t)tm * K + k0 + kk * 32;
    const int s = half * 512 + tid;
    const int row = s >> 2;
    const int cg = (s & 3) ^ ((s >> 3) & 3);   // source pre-swizzle
    async16(g + (size_t)row * K + cg * 8, blk + (size_t)s * 8);
  };
  auto stageB1 = [&](int buf, int kk, int k0, int half) {
    unsigned short* blk = lds + buf * BUFUS + 2 * AUS + kk * BUS;
    const unsigned short* g = Bt + (size_t)tn * K + k0 + kk * 32;
    const int s = half * 512 + tid;
    const int row = s >> 2;
    const int cg = (s & 3) ^ ((s >> 3) & 3);
    async16(g + (size_t)row * K + cg * 8, blk + (size_t)s * 8);
  };
  auto stageBb = [&](int buf, int kk, int k0) {   // 2nd B half only when BN=256
    if constexpr (BN == 256) stageB1(buf, kk, k0, 1);
  };
  auto rdA = [&](int buf, int kk, int mi) -> bf16x8 {
    return *(const bf16x8*)(lds + buf * BUFUS + kk * AUS + (wm + mi * 16 + r15) * 32 + cus);
  };
  auto rdB = [&](int buf, int kk, int ni) -> bf16x8 {
    return *(const bf16x8*)(lds + buf * BUFUS + 2 * AUS + kk * BUS + (wn + ni * 16 + r15) * 32 + cus);
  };

  bf16x8 af[4], bq[NI];
  constexpr int VMS = (BN == 256) ? 8 : 6;       // steady-state counted wait
  constexpr int VMP = (BN == 256) ? 4 : 3;       // peel ph4-end wait

#define PH(buf, kk, mh, BREAD, WAIT, ...)                                       \
  {                                                                             \
    _Pragma("unroll")                                                           \
    for (int q = 0; q < 4; ++q) af[q] = rdA(buf, kk, (mh) * 4 + q);             \
    if (BREAD) {                                                                \
      _Pragma("unroll")                                                         \
      for (int n = 0; n < NI; ++n) bq[n] = rdB(buf, kk, n);                     \
    }                                                                           \
    __VA_ARGS__;                                                                \
    bar(); LGKM0;                                                               \
    __builtin_amdgcn_s_setprio(1);                                              \
    _Pragma("unroll")                                                           \
    for (int q = 0; q < 4; ++q)                                                 \
      _Pragma("unroll")                                                         \
      for (int n = 0; n < NI; ++n)                                              \
        acc[(mh) * 4 + q][n] = MFMA_BF16(af[q], bq[n], acc[(mh) * 4 + q][n], 0, 0, 0); \
    __builtin_amdgcn_s_setprio(0);                                              \
    WAIT;                                                                       \
    bar();                                                                      \
  }

  // prologue: t0 (buf0) fully + t1.kk0 (buf1); t1.kk1 staged in iter0 ph1-2
  stageA1(0, 0, 0, 0); stageA1(0, 0, 0, 1); stageB1(0, 0, 0, 0); stageBb(0, 0, 0);
  stageA1(0, 1, 0, 0); stageA1(0, 1, 0, 1); stageB1(0, 1, 0, 0); stageBb(0, 1, 0);
  stageA1(1, 0, 64, 0); stageA1(1, 0, 64, 1); stageB1(1, 0, 64, 0); stageBb(1, 0, 64);
  vmwait<VMS>();
  bar();

  for (int i = 0; i < NT / 2 - 1; ++i) {
    const int kb = (2 * i + 1) * 64, kc = kb + 64, kd = kc + 64;
    PH(0, 0, 0, 1, ((void)0),    stageA1(1, 1, kb, 0); stageA1(1, 1, kb, 1))
    PH(0, 0, 1, 0, vmwait<VMS>(), stageB1(1, 1, kb, 0); stageBb(1, 1, kb))
    PH(0, 1, 0, 1, ((void)0),    stageA1(0, 0, kc, 0); stageA1(0, 0, kc, 1))
    PH(0, 1, 1, 0, vmwait<VMS>(), stageB1(0, 0, kc, 0); stageBb(0, 0, kc))
    PH(1, 0, 0, 1, ((void)0),    stageA1(0, 1, kc, 0); stageA1(0, 1, kc, 1))
    PH(1, 0, 1, 0, vmwait<VMS>(), stageB1(0, 1, kc, 0); stageBb(0, 1, kc))
    PH(1, 1, 0, 1, ((void)0),    stageA1(1, 0, kd, 0); stageA1(1, 0, kd, 1))
    PH(1, 1, 1, 0, vmwait<VMS>(), stageB1(1, 0, kd, 0); stageBb(1, 0, kd))
  }

  { // peeled last iteration: only t(NT-1).kk1 still needs staging
    const int kb = (NT - 1) * 64;
    PH(0, 0, 0, 1, ((void)0),    stageA1(1, 1, kb, 0); stageA1(1, 1, kb, 1))
    PH(0, 0, 1, 0, vmwait<VMS>(), stageB1(1, 1, kb, 0); stageBb(1, 1, kb))
    PH(0, 1, 0, 1, ((void)0),    ((void)0))
    PH(0, 1, 1, 0, vmwait<VMP>(), ((void)0))
    PH(1, 0, 0, 1, ((void)0),    ((void)0))
    PH(1, 0, 1, 0, vmwait<0>(),  ((void)0))
    PH(1, 1, 0, 1, ((void)0),    ((void)0))
    PH(1, 1, 1, 0, ((void)0),    ((void)0))
  }
#undef PH

  // ---- epilogue: stage C through LDS, then coalesced stores ----
  const int rg = (lane >> 4) * 4;
  float bias_r[NI];
  #pragma unroll
  for (int ni = 0; ni < NI; ++ni) bias_r[ni] = bias[tn + wn + ni * 16 + r15];

  bar();
  if constexpr (EPI == 0) {
    unsigned short* C = lds;   // 256 x 256 bf16, col-swizzled per row
    #pragma unroll
    for (int mi = 0; mi < 8; ++mi)
      #pragma unroll
      for (int ni = 0; ni < NI; ++ni) {
        const int c0 = wn + ni * 16 + r15;
        #pragma unroll
        for (int j = 0; j < 4; ++j) {
          const int r = wm + mi * 16 + rg + j;
          const int key = (((r & 3) ^ ((r >> 2) & 3)) << 4);
          float v = acc[mi][ni][j] + bias_r[ni];
          v = v / (1.f + __expf(-v));
          C[r * 256 + (c0 ^ key)] = f2bf(v);
        }
      }
    bar();
    #pragma unroll
    for (int i = 0; i < 16; ++i) {
      const int off = i * 4096 + tid * 8;
      const int r = off >> 8;
      const int pc = off & 255;
      const int key = (((r & 3) ^ ((r >> 2) & 3)) << 4);
      bf16x8 v = *(const bf16x8*)(C + off);
      *(bf16x8*)((unsigned short*)outp + (size_t)(tm + r) * N + tn + (pc ^ key)) = v;
    }
  } else {
    float* C = (float*)lds;    // 256 x 128 f32, col-swizzled per row
    #pragma unroll
    for (int mi = 0; mi < 8; ++mi)
      #pragma unroll
      for (int ni = 0; ni < NI; ++ni) {
        const int c0 = wn + ni * 16 + r15;
        #pragma unroll
        for (int j = 0; j < 4; ++j) {
          const int r = wm + mi * 16 + rg + j;
          const int key = (((r & 3) ^ ((r >> 2) & 3)) << 4);
          C[r * 128 + (c0 ^ key)] = acc[mi][ni][j] + bias_r[ni];
        }
      }
    bar();
    #pragma unroll
    for (int i = 0; i < 16; ++i) {
      const int off = i * 2048 + tid * 4;
      const int r = off >> 7;
      const int pc = off & 127;
      const int key = (((r & 3) ^ ((r >> 2) & 3)) << 4);
      f32x4 v = *(const f32x4*)(C + off);
      const size_t gaddr = (size_t)(tm + r) * N + tn + (pc ^ key);
      f32x4 rv = *(const f32x4*)(resid + gaddr);
      v += rv;
      *(f32x4*)((float*)outp + gaddr) = v;
    }
  }
}

// ---------------- launch ----------------
extern "C" void kernel_launch(void* const* d_in, const int* in_sizes, int n_in,
                              void* d_out, int out_size, void* d_ws, size_t ws_size,
                              hipStream_t stream) {
  const float* x           = (const float*)d_in[0];
  const float* ln_g        = (const float*)d_in[1];
  const float* ln_b        = (const float*)d_in[2];
  const float* phazor      = (const float*)d_in[3];
  const float* phazor_init = (const float*)d_in[4];
  const float* w1          = (const float*)d_in[5];
  const float* b1          = (const float*)d_in[6];
  const float* w2          = (const float*)d_in[7];
  const float* b2          = (const float*)d_in[8];
  const float* last_re     = (const float*)d_in[9];
  const float* last_im     = (const float*)d_in[10];
  float* out = (float*)d_out;
  char* ws = (char*)d_ws;
  const size_t MB = 1ull << 20;

  float* x2  = (float*)(ws);                         // 32 MB
  float* mu1 = (float*)(ws + 32 * MB);               // 32 KB
  float* rs1 = (float*)(ws + 32 * MB + 64 * 1024);
  float* Sre = (float*)(ws + 32 * MB + 256 * 1024);  // 512 KB each
  float* Sim = (float*)(ws + 32 * MB + 768 * 1024);
  float* tokstat = (float*)(ws + 32 * MB + 1280 * 1024);  // 64 KB
  unsigned short* h2  = (unsigned short*)(ws + 35 * MB);   // 16 MB
  unsigned short* hid = (unsigned short*)(ws + 51 * MB);   // 64 MB
  unsigned short* w1t = (unsigned short*)(ws + 115 * MB);  // 8 MB
  unsigned short* w2t = (unsigned short*)(ws + 123 * MB);  // 8 MB

  prep<<<16384, 256, 0, stream>>>(w1, w2, w1t, w2t, x, mu1, rs1, tokstat);
  scan_phase1<<<dim3(DIMC / 256, NCHUNK, BSZ), 256, 0, stream>>>(x, mu1, rs1, ln_g, ln_b,
                                                                 phazor, Sre, Sim);
  scan_phase3<<<dim3(DIMC / 256, NCHUNK, BSZ), 256, 0, stream>>>(x, mu1, rs1, ln_g, ln_b, phazor,
                                                                 phazor_init, last_re, last_im,
                                                                 Sre, Sim, x2, tokstat);
  ln_apply<<<NTOK, 256, 0, stream>>>(x2, tokstat, ln_g, ln_b, h2);

  gemm8<256, 0><<<(NTOK / 256) * (DFFC / 256), 512, 0, stream>>>(h2, w1t, b1, nullptr, hid,
                                                                 NTOK, DFFC, DIMC);
  gemm8<128, 1><<<(NTOK / 256) * (DIMC / 128), 512, 0, stream>>>(hid, w2t, b2, x2, out,
                                                                 NTOK, DIMC, DFFC);
}